// Round 5
// baseline (120.704 us; speedup 1.0000x reference)
//
#include <hip/hip_runtime.h>

// CrossProductLayer: out[b, f] = t(b, f) * w[f]
//   f in [0,128)    : x[b,f]^2
//   f in [128,256)  : x[b,f-128]
//   f in [256,8384) : x[b,i]*x[b,j]*0.5, (i,j) = triu_indices(128, k=1)[f-256]
// B=16384, F=8384. 549 MB fp32 output -> HBM-write-bound.
//
// R5: test the WRITE-CONTIGUITY hypothesis. Each block owns 16 FULL rows and
// sweeps each 33.5 KB row contiguously with dword stores (dword > dwordx4
// empirically: R2=101.7 vs R4=110.6 with identical LDS behavior). Feature
// metadata (packed ij + prescaled w) is decoded once by a setup kernel into
// d_ws, then copied to LDS per block so the sweep has no global-latency deps.
// All LDS reads are lane-stride-1 or broadcast (conflict-free). Sentinel 1.0
// at word 128 of each x-row makes the loop branch-free: out = xi*xj*ws.
// fp-exact: *1.0 exact; (xi*xj)*(0.5*w) == ((xi*xj)*0.5)*w (absmax 0.0 in R3/R4).

constexpr int BATCH = 16384;
constexpr int NIN   = 128;
constexpr int NPAIR = NIN * (NIN - 1) / 2;   // 8128
constexpr int NFEAT = 2 * NIN + NPAIR;       // 8384
constexpr int TPB   = 256;
constexpr int ROWS  = 16;                    // full rows per block
constexpr int RS    = 132;                   // x-row stride (words); word 128 = 1.0

__device__ __forceinline__ int pair_off(int i) { return i * (NIN - 1) - (i * (i - 1)) / 2; }

__device__ __forceinline__ void decode_f(int f, float w, int& i, int& j, float& ws) {
    if (f < NIN)          { i = f;       j = f;   ws = w; }
    else if (f < 2 * NIN) { i = f - NIN; j = 128; ws = w; }   // sentinel column
    else {
        const int p = f - 2 * NIN;
        float s = sqrtf((float)(65025 - 8 * p));
        int  ii = (int)((255.0f - s) * 0.5f);
        ii = min(max(ii, 0), NIN - 2);
        while (pair_off(ii + 1) <= p) ++ii;   // exact integer fix-up
        while (pair_off(ii)     >  p) --ii;
        i = ii; j = ii + 1 + (p - pair_off(ii));
        ws = w * 0.5f;                        // exact scaling
    }
}

__global__ void setup_kernel(const float* __restrict__ w,
                             unsigned int* __restrict__ gij,
                             float* __restrict__ gws) {
    const int f = blockIdx.x * TPB + threadIdx.x;
    if (f >= NFEAT) return;
    int i, j; float ws;
    decode_f(f, w[f], i, j, ws);
    gij[f] = (unsigned int)((i << 8) | j);
    gws[f] = ws;
}

template <bool USE_WS>
__global__ __launch_bounds__(TPB) void cpl_kernel(const float* __restrict__ x,
                                                  const float* __restrict__ w,
                                                  const unsigned int* __restrict__ gij,
                                                  const float* __restrict__ gws,
                                                  float* __restrict__ out) {
    __shared__ unsigned int ijs[NFEAT];   // 33.5 KB
    __shared__ float        wss[NFEAT];   // 33.5 KB
    __shared__ float        xs[ROWS * RS];// 8.4 KB

    const int tid = threadIdx.x;
    const int r0  = blockIdx.x * ROWS;

    // Stage 16x128 x-tile (512 float4; 2 per thread). RS*4=528 is 16B-aligned.
#pragma unroll
    for (int p = 0; p < 2; ++p) {
        const int idx = p * TPB + tid;           // 0..511
        const int r = idx >> 5, c4 = (idx & 31) * 4;
        float4 v = *reinterpret_cast<const float4*>(x + (size_t)(r0 + r) * NIN + c4);
        *reinterpret_cast<float4*>(&xs[r * RS + c4]) = v;
    }
    if (tid < ROWS) xs[tid * RS + 128] = 1.0f;   // sentinel for singles

    // Stage metadata tables into LDS.
    if (USE_WS) {
        const uint4*  sij = reinterpret_cast<const uint4*>(gij);
        const float4* sws = reinterpret_cast<const float4*>(gws);
        uint4*  dij = reinterpret_cast<uint4*>(ijs);
        float4* dws = reinterpret_cast<float4*>(wss);
        for (int t = tid; t < NFEAT / 4; t += TPB) {  // 2096 vec4 each
            dij[t] = sij[t];
            dws[t] = sws[t];
        }
    } else {
        for (int f = tid; f < NFEAT; f += TPB) {
            int i, j; float ws;
            decode_f(f, w[f], i, j, ws);
            ijs[f] = (unsigned int)((i << 8) | j);
            wss[f] = ws;
        }
    }
    __syncthreads();

    // Contiguous sweep: each of the 16 rows is written as one 33.5 KB
    // front-to-back stream of aligned 256 B wave-stores.
    for (int r = 0; r < ROWS; ++r) {
        const float* xr   = &xs[r * RS];
        float*       orow = out + (size_t)(r0 + r) * NFEAT;
#pragma unroll 4
        for (int k = 0; k < 32; ++k) {           // f = k*256+tid <= 8191 < NFEAT
            const int f = k * TPB + tid;
            const unsigned int e = ijs[f];
            orow[f] = xr[e >> 8] * xr[e & 255] * wss[f];
        }
        {   // tail chunk: f in [8192, 8384) -> waves 0-2 active, wave 3 idle
            const int f = 32 * TPB + tid;
            if (f < NFEAT) {
                const unsigned int e = ijs[f];
                orow[f] = xr[e >> 8] * xr[e & 255] * wss[f];
            }
        }
    }
}

extern "C" void kernel_launch(void* const* d_in, const int* in_sizes, int n_in,
                              void* d_out, int out_size, void* d_ws, size_t ws_size,
                              hipStream_t stream) {
    const float* x = (const float*)d_in[0];  // [16384, 128]
    const float* w = (const float*)d_in[1];  // [8384]
    float*     out = (float*)d_out;          // [16384, 8384]

    unsigned int* gij = (unsigned int*)d_ws;
    float*        gws = (float*)((char*)d_ws + (size_t)NFEAT * sizeof(unsigned int));
    const size_t  need = (size_t)NFEAT * 8;

    const dim3 grid(BATCH / ROWS);  // 1024 blocks

    if (ws_size >= need) {
        setup_kernel<<<(NFEAT + TPB - 1) / TPB, TPB, 0, stream>>>(w, gij, gws);
        cpl_kernel<true><<<grid, TPB, 0, stream>>>(x, w, gij, gws, out);
    } else {
        cpl_kernel<false><<<grid, TPB, 0, stream>>>(x, w, gij, gws, out);
    }
}